// Round 7
// baseline (351.402 us; speedup 1.0000x reference)
//
#include <hip/hip_runtime.h>
#include <math.h>

#define FB 512
#define TB 256
#define PLANE (FB * TB)
typedef long long i64;
typedef _Float16 f16;
typedef _Float16 f16x8 __attribute__((ext_vector_type(8)));
typedef _Float16 f16x4 __attribute__((ext_vector_type(4)));
typedef float f32x4 __attribute__((ext_vector_type(4)));

#define MFMA16(a, b, c) __builtin_amdgcn_mfma_f32_16x16x32_f16(a, b, c, 0, 0, 0)

// ---------- Weff = W2 @ W1  (f32 accum, f16 out)
__global__ __launch_bounds__(256) void k_weff(const float* __restrict__ W1,
                                              const float* __restrict__ W2,
                                              f16* __restrict__ Weff) {
    const int m = blockIdx.y * 4 + (threadIdx.x >> 6);
    const int k = blockIdx.x * 64 + (threadIdx.x & 63);
    const float* w2r = W2 + (i64)m * FB;
    float acc = 0.f;
#pragma unroll 4
    for (int j = 0; j < FB; ++j) acc = fmaf(w2r[j], W1[(i64)j * FB + k], acc);
    Weff[(i64)m * FB + k] = (f16)acc;
}

// ---------- beff = W2 @ b1 + b2 (f32)
__global__ __launch_bounds__(256) void k_beff(const float* __restrict__ W2,
                                              const float* __restrict__ b1,
                                              const float* __restrict__ b2,
                                              float* __restrict__ beff) {
    const int m = blockIdx.x * 256 + threadIdx.x;
    const float* w2r = W2 + (i64)m * FB;
    float acc = b2[m];
#pragma unroll 4
    for (int k = 0; k < FB; ++k) acc = fmaf(w2r[k], b1[k], acc);
    beff[m] = acc;
}

// ---------- x f32 [f][t] -> xh f16 transposed [t][f], per plane, via LDS
__global__ __launch_bounds__(256) void k_transpose_cvt(const float* __restrict__ X,
                                                       f16* __restrict__ O) {
    __shared__ float ld[64][65];
    const int p = blockIdx.z;
    const float* src = X + (i64)p * PLANE;
    f16* dst = O + (i64)p * PLANE;
    const int f0 = blockIdx.y * 64, t0 = blockIdx.x * 64;
    const int tid = threadIdx.x;
    const int lrr = tid >> 4, lc = (tid & 15) * 4;
#pragma unroll
    for (int i = 0; i < 4; ++i) {
        float4 v = *(const float4*)&src[(i64)(f0 + lrr + i * 16) * TB + t0 + lc];
        ld[lrr + i * 16][lc + 0] = v.x;
        ld[lrr + i * 16][lc + 1] = v.y;
        ld[lrr + i * 16][lc + 2] = v.z;
        ld[lrr + i * 16][lc + 3] = v.w;
    }
    __syncthreads();
    const int tr = tid >> 2, fq = tid & 3;
#pragma unroll
    for (int i = 0; i < 4; ++i) {
        const int fl = fq * 16 + i * 4;
        f16x4 o;
#pragma unroll
        for (int j = 0; j < 4; ++j) o[j] = (f16)ld[fl + j][tr];
        *(f16x4*)&dst[(i64)(t0 + tr) * FB + f0 + fl] = o;
    }
}

// ---------- real MFMA GEMM: Out[t][m] (f16) = sum_k A[m][k]*In[t][k] + bias[m]
__global__ __launch_bounds__(256, 2) void k_rgemm(const f16* __restrict__ A,
                                                  const f16* __restrict__ In,
                                                  const float* __restrict__ bias,
                                                  f16* __restrict__ Out) {
    __shared__ f16 Asx[128][40], Bsx[128][40];
    const int slab = blockIdx.z;
    const f16* Bsrc = In + (i64)slab * PLANE;
    f16* Odst = Out + (i64)slab * PLANE;
    const int t0 = blockIdx.x * 128, m0 = blockIdx.y * 128;
    const int tid = threadIdx.x;
    const int wave = tid >> 6, lane = tid & 63;
    const int wm = wave >> 1, wn = wave & 1;
    const int lr = lane & 15, lg = lane >> 4;
    const int srow = tid >> 2, sgrp = (tid & 3) * 8;

    f32x4 acc[4][4] = {};
    f16x8 nA[2], nB[2];
#pragma unroll
    for (int i = 0; i < 2; ++i) {
        const int row = i * 64 + srow;
        nA[i] = *(const f16x8*)(A + (i64)(m0 + row) * FB + sgrp);
        nB[i] = *(const f16x8*)(Bsrc + (i64)(t0 + row) * FB + sgrp);
    }
#pragma unroll
    for (int i = 0; i < 2; ++i) {
        const int row = i * 64 + srow;
        *(f16x8*)&Asx[row][sgrp] = nA[i];
        *(f16x8*)&Bsx[row][sgrp] = nB[i];
    }
    __syncthreads();

#pragma unroll 1
    for (int kt = 0; kt < 16; ++kt) {
        if (kt < 15) {
            const int k0 = (kt + 1) * 32;
#pragma unroll
            for (int i = 0; i < 2; ++i) {
                const int row = i * 64 + srow;
                nA[i] = *(const f16x8*)(A + (i64)(m0 + row) * FB + k0 + sgrp);
                nB[i] = *(const f16x8*)(Bsrc + (i64)(t0 + row) * FB + k0 + sgrp);
            }
        }
        f16x8 aA[4], bB[4];
#pragma unroll
        for (int mf = 0; mf < 4; ++mf)
            aA[mf] = *(const f16x8*)&Asx[wm * 64 + mf * 16 + lr][lg * 8];
#pragma unroll
        for (int nf = 0; nf < 4; ++nf)
            bB[nf] = *(const f16x8*)&Bsx[wn * 64 + nf * 16 + lr][lg * 8];
#pragma unroll
        for (int nf = 0; nf < 4; ++nf)
#pragma unroll
            for (int mf = 0; mf < 4; ++mf)
                acc[mf][nf] = MFMA16(aA[mf], bB[nf], acc[mf][nf]);
        __syncthreads();
        if (kt < 15) {
#pragma unroll
            for (int i = 0; i < 2; ++i) {
                const int row = i * 64 + srow;
                *(f16x8*)&Asx[row][sgrp] = nA[i];
                *(f16x8*)&Bsx[row][sgrp] = nB[i];
            }
        }
        __syncthreads();
    }

#pragma unroll
    for (int mf = 0; mf < 4; ++mf) {
        const int m = m0 + wm * 64 + mf * 16 + lg * 4;
        const float4 bv = *(const float4*)&bias[m];
        const float bb[4] = {bv.x, bv.y, bv.z, bv.w};
#pragma unroll
        for (int nf = 0; nf < 4; ++nf) {
            const int t = t0 + wn * 64 + nf * 16 + lr;
            f16x4 o;
#pragma unroll
            for (int r = 0; r < 4; ++r) o[r] = (f16)(acc[mf][nf][r] + bb[r]);
            *(f16x4*)&Odst[(i64)t * FB + m] = o;
        }
    }
}

// ================= fused softmax + conjFFT/mul/FFT, radix-8 three-step =======
// Arrangement invariant: z[p] at (lane = p%64, reg = p/64); natural in/out.
// PAIRED: every fft512 runs on TWO independent arrays with separate per-wave
// LDS regions, so the two butterfly chains interleave and each LDS transpose
// wait covers both. Twiddles precomputed once per thread (28 VGPRs); forward
// direction negates the sines.

#define TWO_PI_OVER_512 0.012271846303085129f
#define TWO_PI_OVER_64 0.0981747704246810387f
#define R2C 0.70710678118654752f

template <int SGN>
__device__ __forceinline__ void fft8(float xr[8], float xi[8]) {
    const float sg = (float)SGN;   // W8 = e^{SGN*i*2pi/8}
    float t0r = xr[0] + xr[4], t0i = xi[0] + xi[4];
    float u0r = xr[0] - xr[4], u0i = xi[0] - xi[4];
    float t1r = xr[1] + xr[5], t1i = xi[1] + xi[5];
    float d1r = xr[1] - xr[5], d1i = xi[1] - xi[5];
    float u1r = R2C * (d1r - sg * d1i), u1i = R2C * (sg * d1r + d1i);
    float t2r = xr[2] + xr[6], t2i = xi[2] + xi[6];
    float d2r = xr[2] - xr[6], d2i = xi[2] - xi[6];
    float u2r = -sg * d2i, u2i = sg * d2r;
    float t3r = xr[3] + xr[7], t3i = xi[3] + xi[7];
    float d3r = xr[3] - xr[7], d3i = xi[3] - xi[7];
    float u3r = -R2C * (d3r + sg * d3i), u3i = R2C * (sg * d3r - d3i);
    float p0r = t0r + t2r, p0i = t0i + t2i, q0r = t0r - t2r, q0i = t0i - t2i;
    float p1r = t1r + t3r, p1i = t1i + t3i;
    float q1r = -sg * (t1i - t3i), q1i = sg * (t1r - t3r);
    float p2r = u0r + u2r, p2i = u0i + u2i, q2r = u0r - u2r, q2i = u0i - u2i;
    float p3r = u1r + u3r, p3i = u1i + u3i;
    float q3r = -sg * (u1i - u3i), q3i = sg * (u1r - u3r);
    xr[0] = p0r + p1r; xi[0] = p0i + p1i;
    xr[4] = p0r - p1r; xi[4] = p0i - p1i;
    xr[2] = q0r + q1r; xi[2] = q0i + q1i;
    xr[6] = q0r - q1r; xi[6] = q0i - q1i;
    xr[1] = p2r + p3r; xi[1] = p2i + p3i;
    xr[5] = p2r - p3r; xi[5] = p2i - p3i;
    xr[3] = q2r + q3r; xi[3] = q2i + q3i;
    xr[7] = q2r - q3r; xi[7] = q2i - q3i;
}

// paired 512-pt FFT: arrays (a) and (b) with disjoint LDS regions
template <int SGN>
__device__ __forceinline__ void fft512x2(float ar[8], float ai[8],
                                         float br[8], float bi[8], int lane,
                                         float* __restrict__ LaR, float* __restrict__ LaI,
                                         float* __restrict__ LbR, float* __restrict__ LbI,
                                         const float w1c[7], const float w1s[7],
                                         const float w2c[7], const float w2s[7]) {
    const float sg = (float)SGN;
    fft8<SGN>(ar, ai);
    fft8<SGN>(br, bi);
#pragma unroll
    for (int m = 1; m < 8; ++m) {
        const float wc = w1c[m - 1], ws = sg * w1s[m - 1];
        float tr = ar[m], ti = ai[m];
        ar[m] = tr * wc - ti * ws; ai[m] = tr * ws + ti * wc;
        tr = br[m]; ti = bi[m];
        br[m] = tr * wc - ti * ws; bi[m] = tr * ws + ti * wc;
    }
    // transpose 1: (lane=u=a8+8b8, reg=m) -> (lane=a8+8m, reg=b8)
#pragma unroll
    for (int m = 0; m < 8; ++m) {
        LaR[lane * 9 + m] = ar[m]; LaI[lane * 9 + m] = ai[m];
        LbR[lane * 9 + m] = br[m]; LbI[lane * 9 + m] = bi[m];
    }
    {
        const int a8 = lane & 7, m8 = lane >> 3;
#pragma unroll
        for (int b8 = 0; b8 < 8; ++b8) {
            const int src = (a8 + 8 * b8) * 9 + m8;
            ar[b8] = LaR[src]; ai[b8] = LaI[src];
            br[b8] = LbR[src]; bi[b8] = LbI[src];
        }
    }
    fft8<SGN>(ar, ai);
    fft8<SGN>(br, bi);
#pragma unroll
    for (int n = 1; n < 8; ++n) {
        const float wc = w2c[n - 1], ws = sg * w2s[n - 1];
        float tr = ar[n], ti = ai[n];
        ar[n] = tr * wc - ti * ws; ai[n] = tr * ws + ti * wc;
        tr = br[n]; ti = bi[n];
        br[n] = tr * wc - ti * ws; bi[n] = tr * ws + ti * wc;
    }
    // transpose 2: (lane=a8+8m, reg=n) -> (lane=m+8n, reg=a8)
#pragma unroll
    for (int n = 0; n < 8; ++n) {
        LaR[lane * 9 + n] = ar[n]; LaI[lane * 9 + n] = ai[n];
        LbR[lane * 9 + n] = br[n]; LbI[lane * 9 + n] = bi[n];
    }
    {
        const int m2 = lane & 7, n2 = lane >> 3;
#pragma unroll
        for (int a2 = 0; a2 < 8; ++a2) {
            const int src = (a2 + 8 * m2) * 9 + n2;
            ar[a2] = LaR[src]; ai[a2] = LaI[src];
            br[a2] = LbR[src]; bi[a2] = LbI[src];
        }
    }
    fft8<SGN>(ar, ai);
    fft8<SGN>(br, bi);
}

__device__ __forceinline__ float wave_max(float v) {
#pragma unroll
    for (int m = 1; m <= 32; m <<= 1) v = fmaxf(v, __shfl_xor(v, m));
    return v;
}
__device__ __forceinline__ float wave_sum(float v) {
#pragma unroll
    for (int m = 1; m <= 32; m <<= 1) v += __shfl_xor(v, m);
    return v;
}

__device__ __forceinline__ void softmax8(float w[8]) {
    float mx = w[0];
#pragma unroll
    for (int j = 1; j < 8; ++j) mx = fmaxf(mx, w[j]);
    mx = wave_max(mx);
    float sm = 0.f;
#pragma unroll
    for (int j = 0; j < 8; ++j) { w[j] = __expf(w[j] - mx); sm += w[j]; }
    sm = wave_sum(sm);
    const float inv = 1.0f / sm;
#pragma unroll
    for (int j = 0; j < 8; ++j) w[j] *= inv;
}

// grid (32 t-blocks, npairs plane-pairs), block 256 (4 waves, 2 seqs each).
// Phase A: both sequences' conjFFT pairs (h||w) -> products P0, P1;
// Phase B: one paired forward FFT (P0||P1). Writes f32 [t][f] chunk scratch.
__global__ __launch_bounds__(256, 2) void k_fftconv(const f16* __restrict__ xh,
                                                    const f16* __restrict__ logits,
                                                    float* __restrict__ conv,
                                                    int csbase) {
    __shared__ float LDS[4][4][576];   // 36,864 B: 4 waves x 4 arrays
    const int cs = blockIdx.y + csbase;
    const int b = cs >> 4, d = cs & 15;
    const int pre = b * 32 + d;
    const int pim = pre + 16;
    const int chunkoff = (csbase >> 6) * 128;
    const int t0 = blockIdx.x * 8;
    const int tid = threadIdx.x;
    const int wave = tid >> 6, lane = tid & 63;
    float* LaR = LDS[wave][0];
    float* LaI = LDS[wave][1];
    float* LbR = LDS[wave][2];
    float* LbI = LDS[wave][3];

    // twiddle registers (shared by all 3 FFTs of both sequences)
    float w1c[7], w1s[7], w2c[7], w2s[7];
    {
        float s1, c1;
        __sincosf((float)lane * TWO_PI_OVER_512, &s1, &c1);
        w1c[0] = c1; w1s[0] = s1;
#pragma unroll
        for (int m = 1; m < 7; ++m) {
            const float pc = w1c[m - 1], ps = w1s[m - 1];
            w1c[m] = pc * c1 - ps * s1;
            w1s[m] = pc * s1 + ps * c1;
        }
        float s2, c2;
        __sincosf((float)(lane & 7) * TWO_PI_OVER_64, &s2, &c2);
        w2c[0] = c2; w2s[0] = s2;
#pragma unroll
        for (int n = 1; n < 7; ++n) {
            const float pc = w2c[n - 1], ps = w2s[n - 1];
            w2c[n] = pc * c2 - ps * s2;
            w2s[n] = pc * s2 + ps * c2;
        }
    }

    const f16* Hre = xh + (i64)pre * PLANE;
    const f16* Him = xh + (i64)pim * PLANE;
    const f16* Wre = logits + (i64)pre * PLANE;
    const f16* Wim = logits + (i64)pim * PLANE;
    float* Cre = conv + (i64)(pre - chunkoff) * PLANE;
    float* Cim = conv + (i64)(pim - chunkoff) * PLANE;

    const int t1a = t0 + wave * 2;
    const i64 rb0 = (i64)t1a * FB + lane;
    const i64 rb1 = (i64)(t1a + 1) * FB + lane;

    float p0r[8], p0i[8], p1r[8], p1i[8];
    // ---- sequence 0: conjFFT(h) || conjFFT(w) -> P0
    {
        float hr[8], hi2[8], wr[8], wi[8];
#pragma unroll
        for (int j = 0; j < 8; ++j) {
            hr[j] = (float)Hre[rb0 + 64 * j];
            hi2[j] = (float)Him[rb0 + 64 * j];
            wr[j] = (float)Wre[rb0 + 64 * j];
            wi[j] = (float)Wim[rb0 + 64 * j];
        }
        softmax8(wr);
        softmax8(wi);
        fft512x2<1>(hr, hi2, wr, wi, lane, LaR, LaI, LbR, LbI, w1c, w1s, w2c, w2s);
#pragma unroll
        for (int j = 0; j < 8; ++j) {
            p0r[j] = (hr[j] * wr[j] - hi2[j] * wi[j]) * (1.0f / 512.0f);
            p0i[j] = (hr[j] * wi[j] + hi2[j] * wr[j]) * (1.0f / 512.0f);
        }
    }
    // ---- sequence 1: conjFFT(h) || conjFFT(w) -> P1
    {
        float hr[8], hi2[8], wr[8], wi[8];
#pragma unroll
        for (int j = 0; j < 8; ++j) {
            hr[j] = (float)Hre[rb1 + 64 * j];
            hi2[j] = (float)Him[rb1 + 64 * j];
            wr[j] = (float)Wre[rb1 + 64 * j];
            wi[j] = (float)Wim[rb1 + 64 * j];
        }
        softmax8(wr);
        softmax8(wi);
        fft512x2<1>(hr, hi2, wr, wi, lane, LaR, LaI, LbR, LbI, w1c, w1s, w2c, w2s);
#pragma unroll
        for (int j = 0; j < 8; ++j) {
            p1r[j] = (hr[j] * wr[j] - hi2[j] * wi[j]) * (1.0f / 512.0f);
            p1i[j] = (hr[j] * wi[j] + hi2[j] * wr[j]) * (1.0f / 512.0f);
        }
    }
    // ---- paired forward FFT (P0 || P1), natural order out
    fft512x2<-1>(p0r, p0i, p1r, p1i, lane, LaR, LaI, LbR, LbI, w1c, w1s, w2c, w2s);
#pragma unroll
    for (int s = 0; s < 8; ++s) {
        Cre[rb0 + 64 * s] = p0r[s];
        Cim[rb0 + 64 * s] = p0i[s];
        Cre[rb1 + 64 * s] = p1r[s];
        Cim[rb1 + 64 * s] = p1i[s];
    }
}

// ---------- f32 [t][f] -> f32 [f][t] per plane (final output layout)
__global__ __launch_bounds__(256) void k_transpose_out(const float* __restrict__ C,
                                                       float* __restrict__ O,
                                                       int pbase) {
    __shared__ float ld[64][65];
    const int p = blockIdx.z;
    const float* src = C + (i64)p * PLANE;            // [t][f], row stride FB
    float* dst = O + (i64)(p + pbase) * PLANE;        // [f][t], row stride TB
    const int t0 = blockIdx.x * 64, f0 = blockIdx.y * 64;
    const int tid = threadIdx.x;
    const int lrr = tid >> 4, lc = (tid & 15) * 4;
#pragma unroll
    for (int i = 0; i < 4; ++i) {
        float4 v = *(const float4*)&src[(i64)(t0 + lrr + i * 16) * FB + f0 + lc];
        ld[lc + 0][lrr + i * 16] = v.x;
        ld[lc + 1][lrr + i * 16] = v.y;
        ld[lc + 2][lrr + i * 16] = v.z;
        ld[lc + 3][lrr + i * 16] = v.w;
    }
    __syncthreads();
    const int fr = tid >> 4, tc = (tid & 15) * 4;
#pragma unroll
    for (int i = 0; i < 4; ++i) {
        const int f = fr + i * 16;
        float4 o;
        o.x = ld[f][tc + 0]; o.y = ld[f][tc + 1];
        o.z = ld[f][tc + 2]; o.w = ld[f][tc + 3];
        *(float4*)&dst[(i64)(f0 + f) * TB + t0 + tc] = o;
    }
}

extern "C" void kernel_launch(void* const* d_in, const int* in_sizes, int n_in,
                              void* d_out, int out_size, void* d_ws, size_t ws_size,
                              hipStream_t stream) {
    (void)in_sizes; (void)n_in; (void)out_size;
    const float* x = (const float*)d_in[0];
    const float* W1 = (const float*)d_in[1];
    const float* b1 = (const float*)d_in[2];
    const float* W2 = (const float*)d_in[3];
    const float* b2 = (const float*)d_in[4];
    float* out = (float*)d_out;

    char* ws = (char*)d_ws;
    const i64 TENB = (i64)67108864;                       // 33.55M f16 elems * 2B... (f16 tensor bytes)
    f16* Weff = (f16*)(ws);                               // 512 KB
    float* beff = (float*)(ws + 524288);                  // 4 KB pad
    f16* xh = (f16*)(ws + 528384);                        // 67.1 MB
    f16* logits = (f16*)(ws + 528384 + TENB);             // 67.1 MB
    float* conv = (float*)(ws + 528384 + 2 * TENB);       // 67.1 or 134.2 MB

    // fused linear weights: Weff = W2@W1, beff = W2@b1 + b2
    k_weff<<<dim3(8, 128), dim3(256), 0, stream>>>(W1, W2, Weff);
    k_beff<<<dim3(2), dim3(256), 0, stream>>>(W2, b1, b2, beff);
    // x -> f16 [t][f]
    k_transpose_cvt<<<dim3(4, 8, 256), dim3(256), 0, stream>>>(x, xh);
    // logits = Weff @ X + beff
    k_rgemm<<<dim3(TB / 128, FB / 128, 256), dim3(256), 0, stream>>>(Weff, xh, beff, logits);

    const size_t need_full = (size_t)528384 + 2 * (size_t)TENB + (size_t)268435456 / 2; // + 134.2 MB conv
    if (ws_size >= need_full) {
        // single pass: all 128 plane-pairs, conv holds all 256 f32 planes
        k_fftconv<<<dim3(32, 128), dim3(256), 0, stream>>>(xh, logits, conv, 0);
        k_transpose_out<<<dim3(4, 8, 256), dim3(256), 0, stream>>>(conv, out, 0);
    } else {
        // chunk 0: plane-pairs 0..63 (planes 0..127)
        k_fftconv<<<dim3(32, 64), dim3(256), 0, stream>>>(xh, logits, conv, 0);
        k_transpose_out<<<dim3(4, 8, 128), dim3(256), 0, stream>>>(conv, out, 0);
        // chunk 1: plane-pairs 64..127 (planes 128..255)
        k_fftconv<<<dim3(32, 64), dim3(256), 0, stream>>>(xh, logits, conv, 64);
        k_transpose_out<<<dim3(4, 8, 128), dim3(256), 0, stream>>>(conv, out, 128);
    }
}

// Round 8
// 310.583 us; speedup vs baseline: 1.1314x; 1.1314x over previous
//
#include <hip/hip_runtime.h>
#include <math.h>

#define FB 512
#define TB 256
#define PLANE (FB * TB)
typedef long long i64;
typedef _Float16 f16;
typedef _Float16 f16x8 __attribute__((ext_vector_type(8)));
typedef _Float16 f16x4 __attribute__((ext_vector_type(4)));
typedef float f32x4 __attribute__((ext_vector_type(4)));

#define MFMA16(a, b, c) __builtin_amdgcn_mfma_f32_16x16x32_f16(a, b, c, 0, 0, 0)

// ---------- Weff = W2 @ W1  (f32 accum, f16 out)
__global__ __launch_bounds__(256) void k_weff(const float* __restrict__ W1,
                                              const float* __restrict__ W2,
                                              f16* __restrict__ Weff) {
    const int m = blockIdx.y * 4 + (threadIdx.x >> 6);
    const int k = blockIdx.x * 64 + (threadIdx.x & 63);
    const float* w2r = W2 + (i64)m * FB;
    float acc = 0.f;
#pragma unroll 4
    for (int j = 0; j < FB; ++j) acc = fmaf(w2r[j], W1[(i64)j * FB + k], acc);
    Weff[(i64)m * FB + k] = (f16)acc;
}

// ---------- beff = W2 @ b1 + b2 (f32)
__global__ __launch_bounds__(256) void k_beff(const float* __restrict__ W2,
                                              const float* __restrict__ b1,
                                              const float* __restrict__ b2,
                                              float* __restrict__ beff) {
    const int m = blockIdx.x * 256 + threadIdx.x;
    const float* w2r = W2 + (i64)m * FB;
    float acc = b2[m];
#pragma unroll 4
    for (int k = 0; k < FB; ++k) acc = fmaf(w2r[k], b1[k], acc);
    beff[m] = acc;
}

// ---------- x f32 [f][t] -> xh f16 transposed [t][f], per plane, via LDS
__global__ __launch_bounds__(256) void k_transpose_cvt(const float* __restrict__ X,
                                                       f16* __restrict__ O) {
    __shared__ float ld[64][65];
    const int p = blockIdx.z;
    const float* src = X + (i64)p * PLANE;
    f16* dst = O + (i64)p * PLANE;
    const int f0 = blockIdx.y * 64, t0 = blockIdx.x * 64;
    const int tid = threadIdx.x;
    const int lrr = tid >> 4, lc = (tid & 15) * 4;
#pragma unroll
    for (int i = 0; i < 4; ++i) {
        float4 v = *(const float4*)&src[(i64)(f0 + lrr + i * 16) * TB + t0 + lc];
        ld[lrr + i * 16][lc + 0] = v.x;
        ld[lrr + i * 16][lc + 1] = v.y;
        ld[lrr + i * 16][lc + 2] = v.z;
        ld[lrr + i * 16][lc + 3] = v.w;
    }
    __syncthreads();
    const int tr = tid >> 2, fq = tid & 3;
#pragma unroll
    for (int i = 0; i < 4; ++i) {
        const int fl = fq * 16 + i * 4;
        f16x4 o;
#pragma unroll
        for (int j = 0; j < 4; ++j) o[j] = (f16)ld[fl + j][tr];
        *(f16x4*)&dst[(i64)(t0 + tr) * FB + f0 + fl] = o;
    }
}

// ---------- real MFMA GEMM: Out[t][m] (f16) = sum_k A[m][k]*In[t][k] + bias[m]
__global__ __launch_bounds__(256, 2) void k_rgemm(const f16* __restrict__ A,
                                                  const f16* __restrict__ In,
                                                  const float* __restrict__ bias,
                                                  f16* __restrict__ Out) {
    __shared__ f16 Asx[128][40], Bsx[128][40];
    const int slab = blockIdx.z;
    const f16* Bsrc = In + (i64)slab * PLANE;
    f16* Odst = Out + (i64)slab * PLANE;
    const int t0 = blockIdx.x * 128, m0 = blockIdx.y * 128;
    const int tid = threadIdx.x;
    const int wave = tid >> 6, lane = tid & 63;
    const int wm = wave >> 1, wn = wave & 1;
    const int lr = lane & 15, lg = lane >> 4;
    const int srow = tid >> 2, sgrp = (tid & 3) * 8;

    f32x4 acc[4][4] = {};
    f16x8 nA[2], nB[2];
#pragma unroll
    for (int i = 0; i < 2; ++i) {
        const int row = i * 64 + srow;
        nA[i] = *(const f16x8*)(A + (i64)(m0 + row) * FB + sgrp);
        nB[i] = *(const f16x8*)(Bsrc + (i64)(t0 + row) * FB + sgrp);
    }
#pragma unroll
    for (int i = 0; i < 2; ++i) {
        const int row = i * 64 + srow;
        *(f16x8*)&Asx[row][sgrp] = nA[i];
        *(f16x8*)&Bsx[row][sgrp] = nB[i];
    }
    __syncthreads();

#pragma unroll 1
    for (int kt = 0; kt < 16; ++kt) {
        if (kt < 15) {
            const int k0 = (kt + 1) * 32;
#pragma unroll
            for (int i = 0; i < 2; ++i) {
                const int row = i * 64 + srow;
                nA[i] = *(const f16x8*)(A + (i64)(m0 + row) * FB + k0 + sgrp);
                nB[i] = *(const f16x8*)(Bsrc + (i64)(t0 + row) * FB + k0 + sgrp);
            }
        }
        f16x8 aA[4], bB[4];
#pragma unroll
        for (int mf = 0; mf < 4; ++mf)
            aA[mf] = *(const f16x8*)&Asx[wm * 64 + mf * 16 + lr][lg * 8];
#pragma unroll
        for (int nf = 0; nf < 4; ++nf)
            bB[nf] = *(const f16x8*)&Bsx[wn * 64 + nf * 16 + lr][lg * 8];
#pragma unroll
        for (int nf = 0; nf < 4; ++nf)
#pragma unroll
            for (int mf = 0; mf < 4; ++mf)
                acc[mf][nf] = MFMA16(aA[mf], bB[nf], acc[mf][nf]);
        __syncthreads();
        if (kt < 15) {
#pragma unroll
            for (int i = 0; i < 2; ++i) {
                const int row = i * 64 + srow;
                *(f16x8*)&Asx[row][sgrp] = nA[i];
                *(f16x8*)&Bsx[row][sgrp] = nB[i];
            }
        }
        __syncthreads();
    }

#pragma unroll
    for (int mf = 0; mf < 4; ++mf) {
        const int m = m0 + wm * 64 + mf * 16 + lg * 4;
        const float4 bv = *(const float4*)&bias[m];
        const float bb[4] = {bv.x, bv.y, bv.z, bv.w};
#pragma unroll
        for (int nf = 0; nf < 4; ++nf) {
            const int t = t0 + wn * 64 + nf * 16 + lr;
            f16x4 o;
#pragma unroll
            for (int r = 0; r < 4; ++r) o[r] = (f16)(acc[mf][nf][r] + bb[r]);
            *(f16x4*)&Odst[(i64)t * FB + m] = o;
        }
    }
}

// ================= fused softmax + conjFFT/mul/FFT, radix-8 three-step =======
// z[p] at (lane = p%64, reg = p/64); natural in/out. PAIRED arrays (a,b) packed
// with re/im into ONE float4 per transpose element -> single ds_write_b128 +
// ds_read_b128 (4x fewer LDS ops than split-b32). Bank analysis (mod-32 dword):
//   T1 write lane*9+m : 4(lane%8+m)%32 spreads all groups   -> conflict-free
//   T1 read (a+8b)*9+m': 288b vanishes mod32 -> 4(a+m')     -> conflict-free
//   T2 as permuted-READ would collapse (8-way) => restructured as
//   scatter-WRITE (m+8n)*9+a (4(m+a), free) + linear read lane*9+j (free).
// Twiddles in 28 regs, computed once; forward dir flips sine sign.

#define TWO_PI_OVER_512 0.012271846303085129f
#define TWO_PI_OVER_64 0.0981747704246810387f
#define R2C 0.70710678118654752f

template <int SGN>
__device__ __forceinline__ void fft8(float xr[8], float xi[8]) {
    const float sg = (float)SGN;   // W8 = e^{SGN*i*2pi/8}
    float t0r = xr[0] + xr[4], t0i = xi[0] + xi[4];
    float u0r = xr[0] - xr[4], u0i = xi[0] - xi[4];
    float t1r = xr[1] + xr[5], t1i = xi[1] + xi[5];
    float d1r = xr[1] - xr[5], d1i = xi[1] - xi[5];
    float u1r = R2C * (d1r - sg * d1i), u1i = R2C * (sg * d1r + d1i);
    float t2r = xr[2] + xr[6], t2i = xi[2] + xi[6];
    float d2r = xr[2] - xr[6], d2i = xi[2] - xi[6];
    float u2r = -sg * d2i, u2i = sg * d2r;
    float t3r = xr[3] + xr[7], t3i = xi[3] + xi[7];
    float d3r = xr[3] - xr[7], d3i = xi[3] - xi[7];
    float u3r = -R2C * (d3r + sg * d3i), u3i = R2C * (sg * d3r - d3i);
    float p0r = t0r + t2r, p0i = t0i + t2i, q0r = t0r - t2r, q0i = t0i - t2i;
    float p1r = t1r + t3r, p1i = t1i + t3i;
    float q1r = -sg * (t1i - t3i), q1i = sg * (t1r - t3r);
    float p2r = u0r + u2r, p2i = u0i + u2i, q2r = u0r - u2r, q2i = u0i - u2i;
    float p3r = u1r + u3r, p3i = u1i + u3i;
    float q3r = -sg * (u1i - u3i), q3i = sg * (u1r - u3r);
    xr[0] = p0r + p1r; xi[0] = p0i + p1i;
    xr[4] = p0r - p1r; xi[4] = p0i - p1i;
    xr[2] = q0r + q1r; xi[2] = q0i + q1i;
    xr[6] = q0r - q1r; xi[6] = q0i - q1i;
    xr[1] = p2r + p3r; xi[1] = p2i + p3i;
    xr[5] = p2r - p3r; xi[5] = p2i - p3i;
    xr[3] = q2r + q3r; xi[3] = q2i + q3i;
    xr[7] = q2r - q3r; xi[7] = q2i - q3i;
}

// paired 512-pt FFT on arrays (a) and (b), one shared float4 LDS region
template <int SGN>
__device__ __forceinline__ void fft512x2(float ar[8], float ai[8],
                                         float br[8], float bi[8], int lane,
                                         float4* __restrict__ L,
                                         const float w1c[7], const float w1s[7],
                                         const float w2c[7], const float w2s[7]) {
    const float sg = (float)SGN;
    fft8<SGN>(ar, ai);
    fft8<SGN>(br, bi);
#pragma unroll
    for (int m = 1; m < 8; ++m) {
        const float wc = w1c[m - 1], ws = sg * w1s[m - 1];
        float tr = ar[m], ti = ai[m];
        ar[m] = tr * wc - ti * ws; ai[m] = tr * ws + ti * wc;
        tr = br[m]; ti = bi[m];
        br[m] = tr * wc - ti * ws; bi[m] = tr * ws + ti * wc;
    }
    // transpose 1: linear write lane*9+m ; permuted read (a8+8b8)*9+m8
#pragma unroll
    for (int m = 0; m < 8; ++m)
        L[lane * 9 + m] = make_float4(ar[m], ai[m], br[m], bi[m]);
    {
        const int a8 = lane & 7, m8 = lane >> 3;
#pragma unroll
        for (int b8 = 0; b8 < 8; ++b8) {
            const float4 v = L[(a8 + 8 * b8) * 9 + m8];
            ar[b8] = v.x; ai[b8] = v.y; br[b8] = v.z; bi[b8] = v.w;
        }
    }
    fft8<SGN>(ar, ai);
    fft8<SGN>(br, bi);
#pragma unroll
    for (int n = 1; n < 8; ++n) {
        const float wc = w2c[n - 1], ws = sg * w2s[n - 1];
        float tr = ar[n], ti = ai[n];
        ar[n] = tr * wc - ti * ws; ai[n] = tr * ws + ti * wc;
        tr = br[n]; ti = bi[n];
        br[n] = tr * wc - ti * ws; bi[n] = tr * ws + ti * wc;
    }
    // transpose 2: scatter write (m+8n)*9+a ; linear read lane*9+j
    {
        const int a2 = lane & 7, m2 = lane >> 3;
#pragma unroll
        for (int n = 0; n < 8; ++n)
            L[(m2 + 8 * n) * 9 + a2] = make_float4(ar[n], ai[n], br[n], bi[n]);
    }
#pragma unroll
    for (int j = 0; j < 8; ++j) {
        const float4 v = L[lane * 9 + j];
        ar[j] = v.x; ai[j] = v.y; br[j] = v.z; bi[j] = v.w;
    }
    fft8<SGN>(ar, ai);
    fft8<SGN>(br, bi);
}

__device__ __forceinline__ float wave_max(float v) {
#pragma unroll
    for (int m = 1; m <= 32; m <<= 1) v = fmaxf(v, __shfl_xor(v, m));
    return v;
}
__device__ __forceinline__ float wave_sum(float v) {
#pragma unroll
    for (int m = 1; m <= 32; m <<= 1) v += __shfl_xor(v, m);
    return v;
}

__device__ __forceinline__ void softmax8(float w[8]) {
    float mx = w[0];
#pragma unroll
    for (int j = 1; j < 8; ++j) mx = fmaxf(mx, w[j]);
    mx = wave_max(mx);
    float sm = 0.f;
#pragma unroll
    for (int j = 0; j < 8; ++j) { w[j] = __expf(w[j] - mx); sm += w[j]; }
    sm = wave_sum(sm);
    const float inv = 1.0f / sm;
#pragma unroll
    for (int j = 0; j < 8; ++j) w[j] *= inv;
}

// grid (32 t-blocks, 64 plane-pairs per chunk), block 256 (4 waves, 2 seqs each)
__global__ __launch_bounds__(256, 2) void k_fftconv(const f16* __restrict__ xh,
                                                    const f16* __restrict__ logits,
                                                    float* __restrict__ conv,
                                                    int csbase) {
    __shared__ float4 LDS[4][576];     // 36,864 B: one packed region per wave
    const int cs = blockIdx.y + csbase;
    const int b = cs >> 4, d = cs & 15;
    const int pre = b * 32 + d;
    const int pim = pre + 16;
    const int chunkoff = (csbase >> 6) * 128;
    const int t0 = blockIdx.x * 8;
    const int tid = threadIdx.x;
    const int wave = tid >> 6, lane = tid & 63;
    float4* L = LDS[wave];

    // twiddle registers (shared by all 3 paired FFTs)
    float w1c[7], w1s[7], w2c[7], w2s[7];
    {
        float s1, c1;
        __sincosf((float)lane * TWO_PI_OVER_512, &s1, &c1);
        w1c[0] = c1; w1s[0] = s1;
#pragma unroll
        for (int m = 1; m < 7; ++m) {
            const float pc = w1c[m - 1], ps = w1s[m - 1];
            w1c[m] = pc * c1 - ps * s1;
            w1s[m] = pc * s1 + ps * c1;
        }
        float s2, c2;
        __sincosf((float)(lane & 7) * TWO_PI_OVER_64, &s2, &c2);
        w2c[0] = c2; w2s[0] = s2;
#pragma unroll
        for (int n = 1; n < 7; ++n) {
            const float pc = w2c[n - 1], ps = w2s[n - 1];
            w2c[n] = pc * c2 - ps * s2;
            w2s[n] = pc * s2 + ps * c2;
        }
    }

    const f16* Hre = xh + (i64)pre * PLANE;
    const f16* Him = xh + (i64)pim * PLANE;
    const f16* Wre = logits + (i64)pre * PLANE;
    const f16* Wim = logits + (i64)pim * PLANE;
    float* Cre = conv + (i64)(pre - chunkoff) * PLANE;
    float* Cim = conv + (i64)(pim - chunkoff) * PLANE;

    const int t1a = t0 + wave * 2;
    const i64 rb0 = (i64)t1a * FB + lane;
    const i64 rb1 = (i64)(t1a + 1) * FB + lane;

    float p0r[8], p0i[8], p1r[8], p1i[8];
    // ---- sequence 0: conjFFT(h) || conjFFT(w) -> P0
    {
        float hr[8], hi2[8], wr[8], wi[8];
#pragma unroll
        for (int j = 0; j < 8; ++j) {
            hr[j] = (float)Hre[rb0 + 64 * j];
            hi2[j] = (float)Him[rb0 + 64 * j];
            wr[j] = (float)Wre[rb0 + 64 * j];
            wi[j] = (float)Wim[rb0 + 64 * j];
        }
        softmax8(wr);
        softmax8(wi);
        fft512x2<1>(hr, hi2, wr, wi, lane, L, w1c, w1s, w2c, w2s);
#pragma unroll
        for (int j = 0; j < 8; ++j) {
            p0r[j] = (hr[j] * wr[j] - hi2[j] * wi[j]) * (1.0f / 512.0f);
            p0i[j] = (hr[j] * wi[j] + hi2[j] * wr[j]) * (1.0f / 512.0f);
        }
    }
    // ---- sequence 1: conjFFT(h) || conjFFT(w) -> P1
    {
        float hr[8], hi2[8], wr[8], wi[8];
#pragma unroll
        for (int j = 0; j < 8; ++j) {
            hr[j] = (float)Hre[rb1 + 64 * j];
            hi2[j] = (float)Him[rb1 + 64 * j];
            wr[j] = (float)Wre[rb1 + 64 * j];
            wi[j] = (float)Wim[rb1 + 64 * j];
        }
        softmax8(wr);
        softmax8(wi);
        fft512x2<1>(hr, hi2, wr, wi, lane, L, w1c, w1s, w2c, w2s);
#pragma unroll
        for (int j = 0; j < 8; ++j) {
            p1r[j] = (hr[j] * wr[j] - hi2[j] * wi[j]) * (1.0f / 512.0f);
            p1i[j] = (hr[j] * wi[j] + hi2[j] * wr[j]) * (1.0f / 512.0f);
        }
    }
    // ---- paired forward FFT (P0 || P1), natural order out
    fft512x2<-1>(p0r, p0i, p1r, p1i, lane, L, w1c, w1s, w2c, w2s);
#pragma unroll
    for (int s = 0; s < 8; ++s) {
        Cre[rb0 + 64 * s] = p0r[s];
        Cim[rb0 + 64 * s] = p0i[s];
        Cre[rb1 + 64 * s] = p1r[s];
        Cim[rb1 + 64 * s] = p1i[s];
    }
}

// ---------- f32 [t][f] -> f32 [f][t] per plane (final output layout)
__global__ __launch_bounds__(256) void k_transpose_out(const float* __restrict__ C,
                                                       float* __restrict__ O,
                                                       int pbase) {
    __shared__ float ld[64][65];
    const int p = blockIdx.z;
    const float* src = C + (i64)p * PLANE;            // [t][f], row stride FB
    float* dst = O + (i64)(p + pbase) * PLANE;        // [f][t], row stride TB
    const int t0 = blockIdx.x * 64, f0 = blockIdx.y * 64;
    const int tid = threadIdx.x;
    const int lrr = tid >> 4, lc = (tid & 15) * 4;
#pragma unroll
    for (int i = 0; i < 4; ++i) {
        float4 v = *(const float4*)&src[(i64)(t0 + lrr + i * 16) * FB + f0 + lc];
        ld[lc + 0][lrr + i * 16] = v.x;
        ld[lc + 1][lrr + i * 16] = v.y;
        ld[lc + 2][lrr + i * 16] = v.z;
        ld[lc + 3][lrr + i * 16] = v.w;
    }
    __syncthreads();
    const int fr = tid >> 4, tc = (tid & 15) * 4;
#pragma unroll
    for (int i = 0; i < 4; ++i) {
        const int f = fr + i * 16;
        float4 o;
        o.x = ld[f][tc + 0]; o.y = ld[f][tc + 1];
        o.z = ld[f][tc + 2]; o.w = ld[f][tc + 3];
        *(float4*)&dst[(i64)(f0 + f) * TB + t0 + tc] = o;
    }
}

extern "C" void kernel_launch(void* const* d_in, const int* in_sizes, int n_in,
                              void* d_out, int out_size, void* d_ws, size_t ws_size,
                              hipStream_t stream) {
    (void)in_sizes; (void)n_in; (void)out_size; (void)ws_size;
    const float* x = (const float*)d_in[0];
    const float* W1 = (const float*)d_in[1];
    const float* b1 = (const float*)d_in[2];
    const float* W2 = (const float*)d_in[3];
    const float* b2 = (const float*)d_in[4];
    float* out = (float*)d_out;

    char* ws = (char*)d_ws;
    const i64 TENB = (i64)67108864;                       // f16 tensor bytes
    f16* Weff = (f16*)(ws);                               // 512 KB
    float* beff = (float*)(ws + 524288);                  // 4 KB pad
    f16* xh = (f16*)(ws + 528384);                        // 67.1 MB
    f16* logits = (f16*)(ws + 528384 + TENB);             // 67.1 MB
    float* conv = (float*)(ws + 528384 + 2 * TENB);       // 67.1 MB (half planes f32)

    // fused linear weights: Weff = W2@W1, beff = W2@b1 + b2
    k_weff<<<dim3(8, 128), dim3(256), 0, stream>>>(W1, W2, Weff);
    k_beff<<<dim3(2), dim3(256), 0, stream>>>(W2, b1, b2, beff);
    // x -> f16 [t][f]
    k_transpose_cvt<<<dim3(4, 8, 256), dim3(256), 0, stream>>>(x, xh);
    // logits = Weff @ X + beff
    k_rgemm<<<dim3(TB / 128, FB / 128, 256), dim3(256), 0, stream>>>(Weff, xh, beff, logits);

    // chunked: keeps the 67 MB conv scratch L3-resident between producer/consumer
    k_fftconv<<<dim3(32, 64), dim3(256), 0, stream>>>(xh, logits, conv, 0);
    k_transpose_out<<<dim3(4, 8, 128), dim3(256), 0, stream>>>(conv, out, 0);
    k_fftconv<<<dim3(32, 64), dim3(256), 0, stream>>>(xh, logits, conv, 64);
    k_transpose_out<<<dim3(4, 8, 128), dim3(256), 0, stream>>>(conv, out, 128);
}

// Round 9
// 282.992 us; speedup vs baseline: 1.2417x; 1.0975x over previous
//
#include <hip/hip_runtime.h>
#include <math.h>

#define FB 512
#define TB 256
#define PLANE (FB * TB)
typedef long long i64;
typedef _Float16 f16;
typedef _Float16 f16x8 __attribute__((ext_vector_type(8)));
typedef _Float16 f16x4 __attribute__((ext_vector_type(4)));
typedef float f32x4 __attribute__((ext_vector_type(4)));

#define MFMA16(a, b, c) __builtin_amdgcn_mfma_f32_16x16x32_f16(a, b, c, 0, 0, 0)

// ================= role-split prologue: transpose_cvt || weff || beff ========
// bids [0,8192): x f32 [f][t] -> f16 [t][f]; [8192,9216): Weff=W2@W1; last 2: beff
__global__ __launch_bounds__(256) void k_pre(const float* __restrict__ X,
                                             f16* __restrict__ O,
                                             const float* __restrict__ W1,
                                             const float* __restrict__ W2,
                                             f16* __restrict__ Weff,
                                             const float* __restrict__ b1,
                                             const float* __restrict__ b2,
                                             float* __restrict__ beff) {
    __shared__ float ld[64][65];
    const int bid = blockIdx.x;
    const int tid = threadIdx.x;
    if (bid < 8192) {
        const int p = bid >> 5;
        const int f0 = ((bid >> 2) & 7) * 64, t0 = (bid & 3) * 64;
        const float* src = X + (i64)p * PLANE;
        f16* dst = O + (i64)p * PLANE;
        const int lrr = tid >> 4, lc = (tid & 15) * 4;
#pragma unroll
        for (int i = 0; i < 4; ++i) {
            float4 v = *(const float4*)&src[(i64)(f0 + lrr + i * 16) * TB + t0 + lc];
            ld[lrr + i * 16][lc + 0] = v.x;
            ld[lrr + i * 16][lc + 1] = v.y;
            ld[lrr + i * 16][lc + 2] = v.z;
            ld[lrr + i * 16][lc + 3] = v.w;
        }
        __syncthreads();
        const int tr = tid >> 2, fq = tid & 3;
#pragma unroll
        for (int i = 0; i < 4; ++i) {
            const int fl = fq * 16 + i * 4;
            f16x4 o;
#pragma unroll
            for (int j = 0; j < 4; ++j) o[j] = (f16)ld[fl + j][tr];
            *(f16x4*)&dst[(i64)(t0 + tr) * FB + f0 + fl] = o;
        }
    } else if (bid < 9216) {
        const int w = bid - 8192;
        const int m = (w >> 3) * 4 + (tid >> 6);
        const int k = (w & 7) * 64 + (tid & 63);
        const float* w2r = W2 + (i64)m * FB;
        float acc = 0.f;
#pragma unroll 4
        for (int j = 0; j < FB; ++j) acc = fmaf(w2r[j], W1[(i64)j * FB + k], acc);
        Weff[(i64)m * FB + k] = (f16)acc;
    } else {
        const int m = (bid - 9216) * 256 + tid;
        const float* w2r = W2 + (i64)m * FB;
        float acc = b2[m];
#pragma unroll 4
        for (int k = 0; k < FB; ++k) acc = fmaf(w2r[k], b1[k], acc);
        beff[m] = acc;
    }
}

// ---------- real MFMA GEMM: Out[t][m] (f16) = sum_k A[m][k]*In[t][k] + bias[m]
__global__ __launch_bounds__(256, 2) void k_rgemm(const f16* __restrict__ A,
                                                  const f16* __restrict__ In,
                                                  const float* __restrict__ bias,
                                                  f16* __restrict__ Out) {
    __shared__ f16 Asx[128][40], Bsx[128][40];
    const int slab = blockIdx.z;
    const f16* Bsrc = In + (i64)slab * PLANE;
    f16* Odst = Out + (i64)slab * PLANE;
    const int t0 = blockIdx.x * 128, m0 = blockIdx.y * 128;
    const int tid = threadIdx.x;
    const int wave = tid >> 6, lane = tid & 63;
    const int wm = wave >> 1, wn = wave & 1;
    const int lr = lane & 15, lg = lane >> 4;
    const int srow = tid >> 2, sgrp = (tid & 3) * 8;

    f32x4 acc[4][4] = {};
    f16x8 nA[2], nB[2];
#pragma unroll
    for (int i = 0; i < 2; ++i) {
        const int row = i * 64 + srow;
        nA[i] = *(const f16x8*)(A + (i64)(m0 + row) * FB + sgrp);
        nB[i] = *(const f16x8*)(Bsrc + (i64)(t0 + row) * FB + sgrp);
    }
#pragma unroll
    for (int i = 0; i < 2; ++i) {
        const int row = i * 64 + srow;
        *(f16x8*)&Asx[row][sgrp] = nA[i];
        *(f16x8*)&Bsx[row][sgrp] = nB[i];
    }
    __syncthreads();

#pragma unroll 1
    for (int kt = 0; kt < 16; ++kt) {
        if (kt < 15) {
            const int k0 = (kt + 1) * 32;
#pragma unroll
            for (int i = 0; i < 2; ++i) {
                const int row = i * 64 + srow;
                nA[i] = *(const f16x8*)(A + (i64)(m0 + row) * FB + k0 + sgrp);
                nB[i] = *(const f16x8*)(Bsrc + (i64)(t0 + row) * FB + k0 + sgrp);
            }
        }
        f16x8 aA[4], bB[4];
#pragma unroll
        for (int mf = 0; mf < 4; ++mf)
            aA[mf] = *(const f16x8*)&Asx[wm * 64 + mf * 16 + lr][lg * 8];
#pragma unroll
        for (int nf = 0; nf < 4; ++nf)
            bB[nf] = *(const f16x8*)&Bsx[wn * 64 + nf * 16 + lr][lg * 8];
#pragma unroll
        for (int nf = 0; nf < 4; ++nf)
#pragma unroll
            for (int mf = 0; mf < 4; ++mf)
                acc[mf][nf] = MFMA16(aA[mf], bB[nf], acc[mf][nf]);
        __syncthreads();
        if (kt < 15) {
#pragma unroll
            for (int i = 0; i < 2; ++i) {
                const int row = i * 64 + srow;
                *(f16x8*)&Asx[row][sgrp] = nA[i];
                *(f16x8*)&Bsx[row][sgrp] = nB[i];
            }
        }
        __syncthreads();
    }

#pragma unroll
    for (int mf = 0; mf < 4; ++mf) {
        const int m = m0 + wm * 64 + mf * 16 + lg * 4;
        const float4 bv = *(const float4*)&bias[m];
        const float bb[4] = {bv.x, bv.y, bv.z, bv.w};
#pragma unroll
        for (int nf = 0; nf < 4; ++nf) {
            const int t = t0 + wn * 64 + nf * 16 + lr;
            f16x4 o;
#pragma unroll
            for (int r = 0; r < 4; ++r) o[r] = (f16)(acc[mf][nf][r] + bb[r]);
            *(f16x4*)&Odst[(i64)t * FB + m] = o;
        }
    }
}

// ================= fused softmax + conjFFT/mul/FFT, radix-8 three-step =======
// z[p] at (lane = p%64, reg = p/64); natural in/out. Paired arrays packed into
// one float4 per LDS transpose element; conflict-free by construction (r8).

#define TWO_PI_OVER_512 0.012271846303085129f
#define TWO_PI_OVER_64 0.0981747704246810387f
#define R2C 0.70710678118654752f

template <int SGN>
__device__ __forceinline__ void fft8(float xr[8], float xi[8]) {
    const float sg = (float)SGN;   // W8 = e^{SGN*i*2pi/8}
    float t0r = xr[0] + xr[4], t0i = xi[0] + xi[4];
    float u0r = xr[0] - xr[4], u0i = xi[0] - xi[4];
    float t1r = xr[1] + xr[5], t1i = xi[1] + xi[5];
    float d1r = xr[1] - xr[5], d1i = xi[1] - xi[5];
    float u1r = R2C * (d1r - sg * d1i), u1i = R2C * (sg * d1r + d1i);
    float t2r = xr[2] + xr[6], t2i = xi[2] + xi[6];
    float d2r = xr[2] - xr[6], d2i = xi[2] - xi[6];
    float u2r = -sg * d2i, u2i = sg * d2r;
    float t3r = xr[3] + xr[7], t3i = xi[3] + xi[7];
    float d3r = xr[3] - xr[7], d3i = xi[3] - xi[7];
    float u3r = -R2C * (d3r + sg * d3i), u3i = R2C * (sg * d3r - d3i);
    float p0r = t0r + t2r, p0i = t0i + t2i, q0r = t0r - t2r, q0i = t0i - t2i;
    float p1r = t1r + t3r, p1i = t1i + t3i;
    float q1r = -sg * (t1i - t3i), q1i = sg * (t1r - t3r);
    float p2r = u0r + u2r, p2i = u0i + u2i, q2r = u0r - u2r, q2i = u0i - u2i;
    float p3r = u1r + u3r, p3i = u1i + u3i;
    float q3r = -sg * (u1i - u3i), q3i = sg * (u1r - u3r);
    xr[0] = p0r + p1r; xi[0] = p0i + p1i;
    xr[4] = p0r - p1r; xi[4] = p0i - p1i;
    xr[2] = q0r + q1r; xi[2] = q0i + q1i;
    xr[6] = q0r - q1r; xi[6] = q0i - q1i;
    xr[1] = p2r + p3r; xi[1] = p2i + p3i;
    xr[5] = p2r - p3r; xi[5] = p2i - p3i;
    xr[3] = q2r + q3r; xi[3] = q2i + q3i;
    xr[7] = q2r - q3r; xi[7] = q2i - q3i;
}

template <int SGN>
__device__ __forceinline__ void fft512x2(float ar[8], float ai[8],
                                         float br[8], float bi[8], int lane,
                                         float4* __restrict__ L,
                                         const float w1c[7], const float w1s[7],
                                         const float w2c[7], const float w2s[7]) {
    const float sg = (float)SGN;
    fft8<SGN>(ar, ai);
    fft8<SGN>(br, bi);
#pragma unroll
    for (int m = 1; m < 8; ++m) {
        const float wc = w1c[m - 1], ws = sg * w1s[m - 1];
        float tr = ar[m], ti = ai[m];
        ar[m] = tr * wc - ti * ws; ai[m] = tr * ws + ti * wc;
        tr = br[m]; ti = bi[m];
        br[m] = tr * wc - ti * ws; bi[m] = tr * ws + ti * wc;
    }
    // transpose 1: linear write lane*9+m ; permuted read (a8+8b8)*9+m8
#pragma unroll
    for (int m = 0; m < 8; ++m)
        L[lane * 9 + m] = make_float4(ar[m], ai[m], br[m], bi[m]);
    {
        const int a8 = lane & 7, m8 = lane >> 3;
#pragma unroll
        for (int b8 = 0; b8 < 8; ++b8) {
            const float4 v = L[(a8 + 8 * b8) * 9 + m8];
            ar[b8] = v.x; ai[b8] = v.y; br[b8] = v.z; bi[b8] = v.w;
        }
    }
    fft8<SGN>(ar, ai);
    fft8<SGN>(br, bi);
#pragma unroll
    for (int n = 1; n < 8; ++n) {
        const float wc = w2c[n - 1], ws = sg * w2s[n - 1];
        float tr = ar[n], ti = ai[n];
        ar[n] = tr * wc - ti * ws; ai[n] = tr * ws + ti * wc;
        tr = br[n]; ti = bi[n];
        br[n] = tr * wc - ti * ws; bi[n] = tr * ws + ti * wc;
    }
    // transpose 2: scatter write (m+8n)*9+a ; linear read lane*9+j
    {
        const int a2 = lane & 7, m2 = lane >> 3;
#pragma unroll
        for (int n = 0; n < 8; ++n)
            L[(m2 + 8 * n) * 9 + a2] = make_float4(ar[n], ai[n], br[n], bi[n]);
    }
#pragma unroll
    for (int j = 0; j < 8; ++j) {
        const float4 v = L[lane * 9 + j];
        ar[j] = v.x; ai[j] = v.y; br[j] = v.z; bi[j] = v.w;
    }
    fft8<SGN>(ar, ai);
    fft8<SGN>(br, bi);
}

__device__ __forceinline__ float wave_max(float v) {
#pragma unroll
    for (int m = 1; m <= 32; m <<= 1) v = fmaxf(v, __shfl_xor(v, m));
    return v;
}
__device__ __forceinline__ float wave_sum(float v) {
#pragma unroll
    for (int m = 1; m <= 32; m <<= 1) v += __shfl_xor(v, m);
    return v;
}

__device__ __forceinline__ void softmax8(float w[8]) {
    float mx = w[0];
#pragma unroll
    for (int j = 1; j < 8; ++j) mx = fmaxf(mx, w[j]);
    mx = wave_max(mx);
    float sm = 0.f;
#pragma unroll
    for (int j = 0; j < 8; ++j) { w[j] = __expf(w[j] - mx); sm += w[j]; }
    sm = wave_sum(sm);
    const float inv = 1.0f / sm;
#pragma unroll
    for (int j = 0; j < 8; ++j) w[j] *= inv;
}

// fftconv body for one block: t-block tblk (0..31), plane-pair cs, chunk-local conv
__device__ __forceinline__ void fftconv_block(const f16* __restrict__ xh,
                                              const f16* __restrict__ logits,
                                              float* __restrict__ conv,
                                              int tblk, int cs, int chunkoff,
                                              int wave, int lane, float4* L) {
    const int b = cs >> 4, d = cs & 15;
    const int pre = b * 32 + d;
    const int pim = pre + 16;
    const int t0 = tblk * 8;

    float w1c[7], w1s[7], w2c[7], w2s[7];
    {
        float s1, c1;
        __sincosf((float)lane * TWO_PI_OVER_512, &s1, &c1);
        w1c[0] = c1; w1s[0] = s1;
#pragma unroll
        for (int m = 1; m < 7; ++m) {
            const float pc = w1c[m - 1], ps = w1s[m - 1];
            w1c[m] = pc * c1 - ps * s1;
            w1s[m] = pc * s1 + ps * c1;
        }
        float s2, c2;
        __sincosf((float)(lane & 7) * TWO_PI_OVER_64, &s2, &c2);
        w2c[0] = c2; w2s[0] = s2;
#pragma unroll
        for (int n = 1; n < 7; ++n) {
            const float pc = w2c[n - 1], ps = w2s[n - 1];
            w2c[n] = pc * c2 - ps * s2;
            w2s[n] = pc * s2 + ps * c2;
        }
    }

    const f16* Hre = xh + (i64)pre * PLANE;
    const f16* Him = xh + (i64)pim * PLANE;
    const f16* Wre = logits + (i64)pre * PLANE;
    const f16* Wim = logits + (i64)pim * PLANE;
    float* Cre = conv + (i64)(pre - chunkoff) * PLANE;
    float* Cim = conv + (i64)(pim - chunkoff) * PLANE;

    const int t1a = t0 + wave * 2;
    const i64 rb0 = (i64)t1a * FB + lane;
    const i64 rb1 = (i64)(t1a + 1) * FB + lane;

    float p0r[8], p0i[8], p1r[8], p1i[8];
    {
        float hr[8], hi2[8], wr[8], wi[8];
#pragma unroll
        for (int j = 0; j < 8; ++j) {
            hr[j] = (float)Hre[rb0 + 64 * j];
            hi2[j] = (float)Him[rb0 + 64 * j];
            wr[j] = (float)Wre[rb0 + 64 * j];
            wi[j] = (float)Wim[rb0 + 64 * j];
        }
        softmax8(wr);
        softmax8(wi);
        fft512x2<1>(hr, hi2, wr, wi, lane, L, w1c, w1s, w2c, w2s);
#pragma unroll
        for (int j = 0; j < 8; ++j) {
            p0r[j] = (hr[j] * wr[j] - hi2[j] * wi[j]) * (1.0f / 512.0f);
            p0i[j] = (hr[j] * wi[j] + hi2[j] * wr[j]) * (1.0f / 512.0f);
        }
    }
    {
        float hr[8], hi2[8], wr[8], wi[8];
#pragma unroll
        for (int j = 0; j < 8; ++j) {
            hr[j] = (float)Hre[rb1 + 64 * j];
            hi2[j] = (float)Him[rb1 + 64 * j];
            wr[j] = (float)Wre[rb1 + 64 * j];
            wi[j] = (float)Wim[rb1 + 64 * j];
        }
        softmax8(wr);
        softmax8(wi);
        fft512x2<1>(hr, hi2, wr, wi, lane, L, w1c, w1s, w2c, w2s);
#pragma unroll
        for (int j = 0; j < 8; ++j) {
            p1r[j] = (hr[j] * wr[j] - hi2[j] * wi[j]) * (1.0f / 512.0f);
            p1i[j] = (hr[j] * wi[j] + hi2[j] * wr[j]) * (1.0f / 512.0f);
        }
    }
    fft512x2<-1>(p0r, p0i, p1r, p1i, lane, L, w1c, w1s, w2c, w2s);
#pragma unroll
    for (int s = 0; s < 8; ++s) {
        Cre[rb0 + 64 * s] = p0r[s];
        Cim[rb0 + 64 * s] = p0i[s];
        Cre[rb1 + 64 * s] = p1r[s];
        Cim[rb1 + 64 * s] = p1i[s];
    }
}

// transpose_out body: f32 [t][f] chunk plane p -> f32 [f][t] out plane p+pbase
__device__ __forceinline__ void transpose_block(const float* __restrict__ C,
                                                float* __restrict__ O,
                                                int tb, int fb, int p, int pbase,
                                                int tid, float (*ld)[65]) {
    const float* src = C + (i64)p * PLANE;
    float* dst = O + (i64)(p + pbase) * PLANE;
    const int t0 = tb * 64, f0 = fb * 64;
    const int lrr = tid >> 4, lc = (tid & 15) * 4;
#pragma unroll
    for (int i = 0; i < 4; ++i) {
        float4 v = *(const float4*)&src[(i64)(t0 + lrr + i * 16) * FB + f0 + lc];
        ld[lc + 0][lrr + i * 16] = v.x;
        ld[lc + 1][lrr + i * 16] = v.y;
        ld[lc + 2][lrr + i * 16] = v.z;
        ld[lc + 3][lrr + i * 16] = v.w;
    }
    __syncthreads();
    const int fr = tid >> 4, tc = (tid & 15) * 4;
#pragma unroll
    for (int i = 0; i < 4; ++i) {
        const int f = fr + i * 16;
        float4 o;
        o.x = ld[f][tc + 0]; o.y = ld[f][tc + 1];
        o.z = ld[f][tc + 2]; o.w = ld[f][tc + 3];
        *(float4*)&dst[(i64)(f0 + f) * TB + t0 + tc] = o;
    }
}

// ---------- chunk-0 fftconv (pairs 0..63 -> conv0)
__global__ __launch_bounds__(256, 2) void k_fftconv(const f16* __restrict__ xh,
                                                    const f16* __restrict__ logits,
                                                    float* __restrict__ conv) {
    __shared__ float4 LDS[4][576];
    const int wave = threadIdx.x >> 6, lane = threadIdx.x & 63;
    fftconv_block(xh, logits, conv, blockIdx.x, blockIdx.y, 0, wave, lane, LDS[wave]);
}

// ---------- role-split mid: fftconv(pairs 64..127 -> conv1) || transpose(conv0 -> out)
__global__ __launch_bounds__(256, 2) void k_mid(const f16* __restrict__ xh,
                                                const f16* __restrict__ logits,
                                                float* __restrict__ conv1,
                                                const float* __restrict__ conv0,
                                                float* __restrict__ out) {
    __shared__ __align__(16) char raw[36864];
    const int bid = blockIdx.x;
    const int tid = threadIdx.x;
    if (bid < 2048) {
        const int wave = tid >> 6, lane = tid & 63;
        float4* L = (float4*)raw + wave * 576;
        fftconv_block(xh, logits, conv1, bid & 31, 64 + (bid >> 5), 128, wave, lane, L);
    } else {
        const int w = bid - 2048;
        float (*ld)[65] = (float(*)[65])raw;
        transpose_block(conv0, out, w & 3, (w >> 2) & 7, w >> 5, 0, tid, ld);
    }
}

// ---------- final transpose (conv1 -> out planes 128..255)
__global__ __launch_bounds__(256) void k_transpose_out(const float* __restrict__ C,
                                                       float* __restrict__ O,
                                                       int pbase) {
    __shared__ float ld[64][65];
    transpose_block(C, O, blockIdx.x, blockIdx.y, blockIdx.z, pbase, threadIdx.x, ld);
}

extern "C" void kernel_launch(void* const* d_in, const int* in_sizes, int n_in,
                              void* d_out, int out_size, void* d_ws, size_t ws_size,
                              hipStream_t stream) {
    (void)in_sizes; (void)n_in; (void)out_size; (void)ws_size;
    const float* x = (const float*)d_in[0];
    const float* W1 = (const float*)d_in[1];
    const float* b1 = (const float*)d_in[2];
    const float* W2 = (const float*)d_in[3];
    const float* b2 = (const float*)d_in[4];
    float* out = (float*)d_out;

    char* ws = (char*)d_ws;
    const i64 TENB = (i64)67108864;                       // f16 tensor bytes / f32 half-tensor bytes
    f16* Weff = (f16*)(ws);                               // 512 KB
    float* beff = (float*)(ws + 524288);                  // 4 KB pad
    f16* xh = (f16*)(ws + 528384);                        // 67.1 MB
    f16* logits = (f16*)(ws + 528384 + TENB);             // 67.1 MB
    float* conv0 = (float*)(ws + 528384 + 2 * TENB);      // 67.1 MB
    float* conv1 = (float*)(ws + 528384 + 3 * TENB);      // 67.1 MB  (ws >= 269 MB proven r7)

    // L1: transpose_cvt || Weff=W2@W1 || beff=W2@b1+b2
    k_pre<<<dim3(9218), dim3(256), 0, stream>>>(x, xh, W1, W2, Weff, b1, b2, beff);
    // L2: logits = Weff @ X + beff
    k_rgemm<<<dim3(TB / 128, FB / 128, 256), dim3(256), 0, stream>>>(Weff, xh, beff, logits);
    // L3: chunk-0 fftconv -> conv0
    k_fftconv<<<dim3(32, 64), dim3(256), 0, stream>>>(xh, logits, conv0);
    // L4: chunk-1 fftconv -> conv1  ||  transpose conv0 -> out[0:128]
    k_mid<<<dim3(6144), dim3(256), 0, stream>>>(xh, logits, conv1, conv0, out);
    // L5: transpose conv1 -> out[128:256]
    k_transpose_out<<<dim3(4, 8, 128), dim3(256), 0, stream>>>(conv1, out, 128);
}